// Round 15
// baseline (64.472 us; speedup 1.0000x reference)
//
#include <hip/hip_runtime.h>

// Problem constants: B=8, S=1024, E=128, H=32, DK=4.
constexpr int kS = 1024;

typedef __fp16 fp16x2 __attribute__((ext_vector_type(2)));
typedef _Float16 half4v __attribute__((ext_vector_type(4)));
typedef _Float16 half8v __attribute__((ext_vector_type(8)));
typedef float float4v __attribute__((ext_vector_type(4)));

// ---------------------------------------------------------------------------
// Feature-map attention (R14, verified): P[q,k] = e^{q.k/2}, q.k/2 in [-2,2].
// Deg-6 Chebyshev: e^s ~= sum_n b_n s^n (abs err ~4.5e-4) ->
// P = sum_alpha w_a m_q^a m_k^a over 210 monomials (|a|<=6 in 4 vars),
// w_a = b_n * n!/(2^n * a0!a1!a2!a3!).  Attention = two rank-210 contractions:
//   M[a][c]  = sum_k m_k[a]*vv_k[c]   (vv = [z,1]; col 4 = denominator)
//   num[q][c] = sum_a m_q[a] * (w_a M[a][c]);  out = num[0..3]/num[4].
// R15: w folded into M (mreduce) so featC's hot loop is pure FMA — kills
// featC's 420 LDS-ops/thread and any wcoef scratch-array risk.
// ---------------------------------------------------------------------------

__device__ __forceinline__ float wcoef(int a0, int a1, int a2, int a3) {
  const float b[7] = {1.0000101f, 1.0010454f, 0.5001437f, 0.1641115f,
                      0.0413223f, 0.00972570f, 0.00156770f};
  const float f[7] = {1.f, 1.f, 2.f, 6.f, 24.f, 120.f, 720.f};
  const float p2[7] = {1.f, 2.f, 4.f, 8.f, 16.f, 32.f, 64.f};
  int n = a0 + a1 + a2 + a3;
  return b[n] * f[n] / (p2[n] * f[a0] * f[a1] * f[a2] * f[a3]);
}

// Canonical graded enumeration of the 210 monomials. ALL kernels use this
// one generator so indices agree. Fully unrolled: idx and exponents become
// compile-time constants; running products cost ~1.2 mul per monomial.
template <class F>
__device__ __forceinline__ void for_each_mono(float z0, float z1, float z2,
                                              float z3, F&& f) {
  int idx = 0;
  float p0 = 1.f;
#pragma unroll
  for (int a0 = 0; a0 <= 6; ++a0) {
    float p1 = p0;
#pragma unroll
    for (int a1 = 0; a1 <= 6 - a0; ++a1) {
      float p2 = p1;
#pragma unroll
      for (int a2 = 0; a2 <= 6 - a0 - a1; ++a2) {
        float p3 = p2;
#pragma unroll
        for (int a3 = 0; a3 <= 6 - a0 - a1 - a2; ++a3) {
          f(idx, p3, a0, a1, a2, a3);
          ++idx;
          p3 *= z3;
        }
        p2 *= z2;
      }
      p1 *= z1;
    }
    p0 *= z0;
  }
}

// ---------------------------------------------------------------------------
// K1: quantum encoder (analytic collapse, verified R1-R14).
// z0=c1c2c3, z1=c0c1, z2=c0c1c2, z3=c0c1c2c3, c_w=cos(x_w+theta_w).
// h16[bh][s][d] = f16(z_d), unscaled.
// ---------------------------------------------------------------------------
__global__ __launch_bounds__(256) void qenc_kernel(
    const float4* __restrict__ x4, const float* __restrict__ qp,
    uint2* __restrict__ h16u) {
  int idx = blockIdx.x * 256 + threadIdx.x;
  float4 a = x4[idx];
  float c0 = cosf(a.x + qp[0]);
  float c1 = cosf(a.y + qp[1]);
  float c2 = cosf(a.z + qp[2]);
  float c3 = cosf(a.w + qp[3]);
  float z1 = c0 * c1;
  float z2 = z1 * c2;
  float z3 = z2 * c3;
  float z0 = c1 * c2 * c3;
  union { half4v h; uint2 u; } z;
  z.h.x = (_Float16)z0;
  z.h.y = (_Float16)z1;
  z.h.z = (_Float16)z2;
  z.h.w = (_Float16)z3;
  int b = idx >> 15;
  int s = (idx >> 5) & (kS - 1);
  int head = idx & 31;
  int bh = b * 32 + head;
  h16u[(bh << 10) + s] = z.u;
}

// ---------------------------------------------------------------------------
// K2a: M[bh][half][alpha][c] partials (verified R14). Block = (bh, half of
// 512 keys), 4 chunks of 128. Phase1: 2 threads/token -> monomials into LDS
// sm (pad 134). Phase2: thread alpha contracts sm row with vv.
// ---------------------------------------------------------------------------
__global__ __launch_bounds__(256) void featM_kernel(
    const _Float16* __restrict__ h16, float* __restrict__ Mpart) {
  __shared__ _Float16 sm[210][134];
  __shared__ float vv[128][4];
  const int bh = blockIdx.x >> 1;
  const int half = blockIdx.x & 1;
  const int t = threadIdx.x;
  const bool hiH = t >= 128;
  const int tok = hiH ? t - 128 : t;
  const uint2* __restrict__ hb = (const uint2*)(h16) + (bh << 10) + (half << 9);

  float acc0 = 0.f, acc1 = 0.f, acc2 = 0.f, acc3 = 0.f, acc4 = 0.f;

  for (int ch = 0; ch < 4; ++ch) {
    {
      union { uint2 u; half4v h; } uz;
      uz.u = hb[(ch << 7) + tok];
      float z0 = (float)uz.h.x, z1 = (float)uz.h.y;
      float z2 = (float)uz.h.z, z3 = (float)uz.h.w;
      if (!hiH) {
        vv[tok][0] = z0; vv[tok][1] = z1; vv[tok][2] = z2; vv[tok][3] = z3;
      }
      for_each_mono(z0, z1, z2, z3,
                    [&](int mi, float m, int, int, int, int) {
                      if (hiH ? (mi >= 105) : (mi < 105))
                        sm[mi][tok] = (_Float16)m;
                    });
    }
    __syncthreads();
    if (t < 210) {
      for (int k = 0; k < 128; ++k) {
        float m = (float)sm[t][k];
        float4 v = *(const float4*)vv[k];  // uniform -> broadcast
        acc0 += m * v.x; acc1 += m * v.y;
        acc2 += m * v.z; acc3 += m * v.w;
        acc4 += m;
      }
    }
    __syncthreads();
  }
  if (t < 210) {
    float* mp = Mpart + (((bh << 1) + half) * 210 + t) * 5;
    mp[0] = acc0; mp[1] = acc1; mp[2] = acc2; mp[3] = acc3; mp[4] = acc4;
  }
}

// ---------------------------------------------------------------------------
// K2a': Mw[bh][alpha][8] = w_alpha * (Mpart_half0 + Mpart_half1), rows padded
// to 32B for aligned b128. w decoded from the canonical enumeration (210
// compile-time compares against runtime t — cheap, runs on 53k lanes once).
// ---------------------------------------------------------------------------
__global__ __launch_bounds__(256) void mreduce_kernel(
    const float* __restrict__ Mpart, float* __restrict__ Mw) {
  const int bh = blockIdx.x;
  const int t = threadIdx.x;
  if (t >= 210) return;
  float w = 0.f;
  for_each_mono(1.f, 1.f, 1.f, 1.f,
                [&](int mi, float, int a0, int a1, int a2, int a3) {
                  if (mi == t) w = wcoef(a0, a1, a2, a3);
                });
  const float* m0 = Mpart + ((bh << 1) * 210 + t) * 5;
  const float* m1 = m0 + 210 * 5;
  float* o = Mw + (bh * 210 + t) * 8;
#pragma unroll
  for (int c = 0; c < 5; ++c) o[c] = w * (m0[c] + m1[c]);
  o[5] = 0.f; o[6] = 0.f; o[7] = 0.f;
}

// ---------------------------------------------------------------------------
// K2b: out_num[q] = m_q . Mw ; out = num/den. Block = (bh, q-chunk 256).
// No LDS, no sync: Mw rows read at block-uniform addresses (s_load / L1
// broadcast), hot loop = 1 mul + 5 FMA per monomial, fully unrolled.
// ---------------------------------------------------------------------------
__global__ __launch_bounds__(256) void featC_kernel(
    const _Float16* __restrict__ h16, const float* __restrict__ Mw,
    uint2* __restrict__ o16u2) {
  const int bh = blockIdx.x >> 2;
  const int qc = blockIdx.x & 3;
  const int t = threadIdx.x;
  const float* __restrict__ mw = Mw + bh * 210 * 8;

  const int q = (qc << 8) + t;
  union { uint2 u; half4v h; } uz;
  uz.u = ((const uint2*)h16)[(bh << 10) + q];
  float z0 = (float)uz.h.x, z1 = (float)uz.h.y;
  float z2 = (float)uz.h.z, z3 = (float)uz.h.w;

  float n0 = 0.f, n1 = 0.f, n2 = 0.f, n3 = 0.f, den = 0.f;
  for_each_mono(z0, z1, z2, z3,
                [&](int mi, float m, int, int, int, int) {
                  float4 M4 = *(const float4*)(mw + (mi << 3));
                  float M5 = mw[(mi << 3) + 4];
                  n0 += m * M4.x; n1 += m * M4.y;
                  n2 += m * M4.z; n3 += m * M4.w;
                  den += m * M5;
                });

  float inv = 1.0f / den;
  union { fp16x2 p[2]; uint2 u; } res;
  res.p[0] = __builtin_amdgcn_cvt_pkrtz(n0 * inv, n1 * inv);
  res.p[1] = __builtin_amdgcn_cvt_pkrtz(n2 * inv, n3 * inv);
  int b = bh >> 5, head = bh & 31;
  o16u2[(((b << 10) + q) << 5) + head] = res.u;
}

// ---------------------------------------------------------------------------
// K0: pack W into B-fragment layout wtb[e>>3][col][e&7] (f16) for the
// combine MFMA: B[k=e][col] = W[col][e].
// ---------------------------------------------------------------------------
__global__ __launch_bounds__(256) void wtb_kernel(
    const float* __restrict__ W, _Float16* __restrict__ wtb) {
  int i = blockIdx.x * 256 + threadIdx.x;  // 16384
  int col = i >> 7, e = i & 127;
  wtb[((e >> 3) << 10) + (col << 3) + (e & 7)] = (_Float16)W[i];
}

// ---------------------------------------------------------------------------
// K3: combine GEMM out[8192][128] = o16 @ W^T via mfma_f32_16x16x32_f16.
// One wave per 16x16 tile. (verified R6-R14: ~3 us)
// ---------------------------------------------------------------------------
__global__ __launch_bounds__(256) void combine_kernel(
    const _Float16* __restrict__ o16, const _Float16* __restrict__ wtb,
    float* __restrict__ out) {
  const int lane = threadIdx.x & 63;
  const int wv = threadIdx.x >> 6;
  const int job = blockIdx.x * 4 + wv;  // 0..4095
  const int rt = job >> 3, ct = job & 7;
  const int c = lane & 15, g = lane >> 4;
  const uint4* a4 = (const uint4*)o16;
  const uint4* b4 = (const uint4*)wtb;
  const int arow = (rt << 4) + c;
  union U4H { uint4 u; half8v h; };
  float4v acc = {};
#pragma unroll
  for (int t = 0; t < 4; ++t) {
    U4H ua, ub;
    ua.u = a4[(arow << 4) + (t << 2) + g];
    ub.u = b4[(((t << 2) + g) << 7) + (ct << 4) + c];
    acc = __builtin_amdgcn_mfma_f32_16x16x32_f16(ua.h, ub.h, acc, 0, 0, 0);
  }
  const int orow = (rt << 4) + (g << 2);
  const int ocol = (ct << 4) + c;
#pragma unroll
  for (int reg = 0; reg < 4; ++reg)
    out[(orow + reg) * 128 + ocol] = acc[reg];
}

extern "C" void kernel_launch(void* const* d_in, const int* in_sizes, int n_in,
                              void* d_out, int out_size, void* d_ws,
                              size_t ws_size, hipStream_t stream) {
  const float* x = (const float*)d_in[0];   // [8,1024,128] f32
  const float* qp = (const float*)d_in[1];  // [1,4] f32
  const float* W = (const float*)d_in[2];   // [128,128] f32
  float* out = (float*)d_out;               // [8,1024,128] f32

  char* ws = (char*)d_ws;
  _Float16* h16 = (_Float16*)ws;                 // [256][1024][4] f16 = 2 MB
  float* Mpart = (float*)(ws + (2 << 20));       // [256][2][210][5] f32 ~2.1MB
  float* Mw = (float*)(ws + (5 << 20));          // [256][210][8] f32 ~1.7MB
  _Float16* o16 = (_Float16*)(ws + (7 << 20));   // [8192][128] f16 = 2 MB
  _Float16* wtb = (_Float16*)(ws + (9 << 20));   // [16][128][8] f16 = 32 KB

  wtb_kernel<<<64, 256, 0, stream>>>(W, wtb);
  qenc_kernel<<<1024, 256, 0, stream>>>((const float4*)x, qp, (uint2*)h16);
  featM_kernel<<<512, 256, 0, stream>>>(h16, Mpart);
  mreduce_kernel<<<256, 256, 0, stream>>>(Mpart, Mw);
  featC_kernel<<<1024, 256, 0, stream>>>(h16, Mw, (uint2*)o16);
  combine_kernel<<<1024, 256, 0, stream>>>(o16, wtb, out);
}